// Round 10
// baseline (101.043 us; speedup 1.0000x reference)
//
#include <hip/hip_runtime.h>
#include <hip/hip_bf16.h>
#include <hip/hip_cooperative_groups.h>

namespace cg = cooperative_groups;

// CEKT: y_t = sigmoid([h_t|e_t|x] @ Wp + bp)
//   h_t = (1-g)*prev_h + g*tanh(comb @ Wh + bh),  g = sigmoid(comb @ Wq + bq)
//   comb = [e_t | r_t | prev_h];  GAT branch is dead code w.r.t. y_t.
//
// Round-10: ONE cooperative kernel. Block b converts weight-chunk b to bf16
// B-frag layout in d_ws (overlapped with A-staging), __threadfence +
// grid.sync, then the r9 body (2-term split-bf16: x*w ~= xh*wh + xl*wh).
// grid.sync absorbs barrier 1. 256 blocks x 1024 thr, 1 block/CU.

typedef short s16x8 __attribute__((ext_vector_type(8)));
typedef float f32x4 __attribute__((ext_vector_type(4)));

constexpr int NKQ = 10;  // K1=320 -> 10 ksteps of 32
constexpr int NKP = 12;  // K2=384 -> 12 ksteps of 32
constexpr int CH_Q = 0, CH_H = 80, CH_P = 160, NCHUNK = 256;

__device__ __forceinline__ ushort bf16_rne(float f) {
    union { float f; uint u; } a; a.f = f;
    return (ushort)((a.u + 0x7FFFu + ((a.u >> 16) & 1u)) >> 16);
}
__device__ __forceinline__ float bf16_to_f(ushort h) {
    union { uint u; float f; } b; b.u = ((uint)h) << 16;
    return b.f;
}
__device__ __forceinline__ void split2(float f, ushort& hi, ushort& lo) {
    hi = bf16_rne(f);
    lo = bf16_rne(f - bf16_to_f(hi));
}

__global__ __launch_bounds__(1024, 1) void cekt_one(
    const float* __restrict__ x,
    const float* __restrict__ e_t,
    const float* __restrict__ r_t,
    const float* __restrict__ prev_h,
    const float* __restrict__ Wq,
    const float* __restrict__ Wh,
    const float* __restrict__ Wp,
    const float* __restrict__ bq,
    const float* __restrict__ bh,
    const float* __restrict__ bp,
    ushort* __restrict__ ws,
    float* __restrict__ out)
{
    __shared__ alignas(16) ushort A1h[NKQ * 64 * 8], A1l[NKQ * 64 * 8];
    __shared__ alignas(16) ushort A2h[NKP * 64 * 8], A2l[NKP * 64 * 8];
    __shared__ f32x4 p1g[8][64], p1c[8][64], p2y[8][64];

    const int t = threadIdx.x;
    const int row0 = blockIdx.x * 16;
    const int w = t >> 6, lane = t & 63;
    const int ct = w & 7, kh = w >> 3;

    const s16x8* whv = (const s16x8*)ws;

    // ---- prep: this block converts weight-chunk blockIdx.x ----
    // frag elem (chunk, l, j):  W[s*32 + (l>>4)*8 + j][ctc*16 + (l&15)]
    if (t < 128) {
        const int chunk = blockIdx.x;
        const int jp = t >> 6, l = t & 63;
        const float* W;
        int s, ctc;
        if (chunk < CH_H)      { W = Wq; ctc = chunk / NKQ;          s = chunk % NKQ; }
        else if (chunk < CH_P) { W = Wh; ctc = (chunk - CH_H) / NKQ; s = (chunk - CH_H) % NKQ; }
        else                   { W = Wp; ctc = (chunk - CH_P) / NKP; s = (chunk - CH_P) % NKP; }
        const int col = ctc * 16 + (l & 15);
        const int kbase = s * 32 + (l >> 4) * 8 + jp * 4;
        ushort hi[4];
#pragma unroll
        for (int j2 = 0; j2 < 4; ++j2)
            hi[j2] = bf16_rne(W[(kbase + j2) * 128 + col]);
        *(uint2*)&ws[(chunk * 64 + l) * 8 + jp * 4] = *(const uint2*)hi;
    }

    // ---- stage A1 (comb1), coalesced float4 per row ----
    for (int i = t; i < 1280; i += 1024) {
        const int row = i / 80, kq4 = i - row * 80;
        const int k0 = kq4 * 4;
        float4 v;
        if (k0 < 128)      v = *(const float4*)&e_t[(row0 + row) * 128 + k0];
        else if (k0 < 192) v = *(const float4*)&r_t[(row0 + row) * 64 + (k0 - 128)];
        else               v = *(const float4*)&prev_h[(row0 + row) * 128 + (k0 - 192)];
        const int s = k0 >> 5, q = (k0 >> 3) & 3, j0 = k0 & 7;
        const int base = (s * 64 + q * 16 + row) * 8 + j0;
        ushort hi4[4], lo4[4];
        split2(v.x, hi4[0], lo4[0]); split2(v.y, hi4[1], lo4[1]);
        split2(v.z, hi4[2], lo4[2]); split2(v.w, hi4[3], lo4[3]);
        *(uint2*)&A1h[base] = *(const uint2*)hi4;
        *(uint2*)&A1l[base] = *(const uint2*)lo4;
    }
    // ---- stage A2 static part (s=4..11: e_t | x), one float4 per thread ----
    {
        const int row = t >> 6, kr = t & 63;
        const int k0 = 128 + kr * 4;            // 128..380
        const float4 v = (k0 < 256)
            ? *(const float4*)&e_t[(row0 + row) * 128 + (k0 - 128)]
            : *(const float4*)&x[(row0 + row) * 128 + (k0 - 256)];
        const int s = k0 >> 5, q = (k0 >> 3) & 3, j0 = k0 & 7;
        const int base = (s * 64 + q * 16 + row) * 8 + j0;
        ushort hi4[4], lo4[4];
        split2(v.x, hi4[0], lo4[0]); split2(v.y, hi4[1], lo4[1]);
        split2(v.z, hi4[2], lo4[2]); split2(v.w, hi4[3], lo4[3]);
        *(uint2*)&A2h[base] = *(const uint2*)hi4;
        *(uint2*)&A2l[base] = *(const uint2*)lo4;
    }

    // ---- make ws writes visible, wait for all blocks' chunks ----
    __threadfence();
    cg::this_grid().sync();     // also block-barrier: A LDS now visible

    // ---- hoist: ALL phase1 B frags (hi only, 5 ksteps x {q,c}) ----
    const int sbeg = kh * 5;
    s16x8 hq[5], hc[5];
#pragma unroll
    for (int si = 0; si < 5; ++si) {
        const int cq = (CH_Q + ct * NKQ + sbeg + si) * 64 + lane;
        const int cc = (CH_H + ct * NKQ + sbeg + si) * 64 + lane;
        hq[si] = whv[cq];
        hc[si] = whv[cc];
    }

    // ---- phase 1: g,cand partials, LDS+MFMA ----
    f32x4 gacc = {0, 0, 0, 0}, cacc = {0, 0, 0, 0};
#pragma unroll
    for (int si = 0; si < 5; ++si) {
        const int s = sbeg + si;
        const s16x8 aH = *(const s16x8*)&A1h[(s * 64 + lane) * 8];
        const s16x8 aL = *(const s16x8*)&A1l[(s * 64 + lane) * 8];
        gacc = __builtin_amdgcn_mfma_f32_16x16x32_bf16(aH, hq[si], gacc, 0, 0, 0);
        cacc = __builtin_amdgcn_mfma_f32_16x16x32_bf16(aH, hc[si], cacc, 0, 0, 0);
        gacc = __builtin_amdgcn_mfma_f32_16x16x32_bf16(aL, hq[si], gacc, 0, 0, 0);
        cacc = __builtin_amdgcn_mfma_f32_16x16x32_bf16(aL, hc[si], cacc, 0, 0, 0);
    }

    // kh1: store partials, then prefetch phase2-static B across barrier2
    s16x8 pH[6];
    if (kh) {
        p1g[ct][lane] = gacc;
        p1c[ct][lane] = cacc;
#pragma unroll
        for (int si = 0; si < 6; ++si)
            pH[si] = whv[(CH_P + ct * NKP + 6 + si) * 64 + lane];
    }
    __syncthreads();                                        // barrier 2

    f32x4 yacc = {0, 0, 0, 0};
    s16x8 rH[6];
    if (!kh) {
        // issue phase2-remainder B loads first; epilogue VALU covers latency
#pragma unroll
        for (int si = 0; si < 6; ++si)
            rH[si] = whv[(CH_P + ct * NKP + si) * 64 + lane];
        // ---- reduce + gate epilogue; h_t written directly in A2-frag layout
        gacc += p1g[ct][lane];
        cacc += p1c[ct][lane];
        const int colL = lane & 15, rg = lane >> 4;
        const int col = ct * 16 + colL;
        const float bqv = bq[col], bhv = bh[col];
        const int s_h = col >> 5, q_h = (col >> 3) & 3, j_h = col & 7;
#pragma unroll
        for (int i2 = 0; i2 < 4; ++i2) {
            const int row = rg * 4 + i2;
            const float ph = prev_h[(row0 + row) * 128 + col];
            const float g = 1.0f / (1.0f + expf(-(gacc[i2] + bqv)));
            const float cd = tanhf(cacc[i2] + bhv);
            const float h = (1.0f - g) * ph + g * cd;
            ushort hh_, hl_;
            split2(h, hh_, hl_);
            const int idx = (s_h * 64 + q_h * 16 + row) * 8 + j_h;
            A2h[idx] = hh_;
            A2l[idx] = hl_;
        }
    } else {
        // ---- phase 2 partials over static ksteps s=6..11 (preloaded B) ----
#pragma unroll
        for (int si = 0; si < 6; ++si) {
            const int s = 6 + si;
            const s16x8 aH = *(const s16x8*)&A2h[(s * 64 + lane) * 8];
            const s16x8 aL = *(const s16x8*)&A2l[(s * 64 + lane) * 8];
            yacc = __builtin_amdgcn_mfma_f32_16x16x32_bf16(aH, pH[si], yacc, 0, 0, 0);
            yacc = __builtin_amdgcn_mfma_f32_16x16x32_bf16(aL, pH[si], yacc, 0, 0, 0);
        }
        p2y[ct][lane] = yacc;
    }
    __syncthreads();                                        // barrier 3

    // ---- phase 2 remainder (s=0..5, contains h_t) + output, kh0 waves ----
    if (!kh) {
        yacc = p2y[ct][lane];
#pragma unroll
        for (int si = 0; si < 6; ++si) {
            const s16x8 aH = *(const s16x8*)&A2h[(si * 64 + lane) * 8];
            const s16x8 aL = *(const s16x8*)&A2l[(si * 64 + lane) * 8];
            yacc = __builtin_amdgcn_mfma_f32_16x16x32_bf16(aH, rH[si], yacc, 0, 0, 0);
            yacc = __builtin_amdgcn_mfma_f32_16x16x32_bf16(aL, rH[si], yacc, 0, 0, 0);
        }
        const int colL = lane & 15, rg = lane >> 4;
        const int col = ct * 16 + colL;
        const float bpv = bp[col];
#pragma unroll
        for (int i2 = 0; i2 < 4; ++i2) {
            const int row = rg * 4 + i2;
            out[(row0 + row) * 128 + col] = 1.0f / (1.0f + expf(-(yacc[i2] + bpv)));
        }
    }
}

extern "C" void kernel_launch(void* const* d_in, const int* in_sizes, int n_in,
                              void* d_out, int out_size, void* d_ws, size_t ws_size,
                              hipStream_t stream) {
    // setup_inputs order:
    // 0:x 1:adj 2:e_t 3:r_t 4:prev_h 5:W_heads 6:a_heads 7:W_out 8:a_out
    // 9:Wq_w 10:Wq_b 11:Wh_w 12:Wh_b 13:Wp_w 14:Wp_b
    const float* x      = (const float*)d_in[0];
    const float* e_t    = (const float*)d_in[2];
    const float* r_t    = (const float*)d_in[3];
    const float* prev_h = (const float*)d_in[4];
    const float* Wq_w   = (const float*)d_in[9];
    const float* Wq_b   = (const float*)d_in[10];
    const float* Wh_w   = (const float*)d_in[11];
    const float* Wh_b   = (const float*)d_in[12];
    const float* Wp_w   = (const float*)d_in[13];
    const float* Wp_b   = (const float*)d_in[14];
    float* out  = (float*)d_out;
    ushort* ws  = (ushort*)d_ws;   // 256 KB used

    void* args[] = { (void*)&x, (void*)&e_t, (void*)&r_t, (void*)&prev_h,
                     (void*)&Wq_w, (void*)&Wh_w, (void*)&Wp_w,
                     (void*)&Wq_b, (void*)&Wh_b, (void*)&Wp_b,
                     (void*)&ws, (void*)&out };
    hipLaunchCooperativeKernel((const void*)cekt_one, dim3(NCHUNK), dim3(1024),
                               args, 0, stream);
}

// Round 11
// 16.262 us; speedup vs baseline: 6.2134x; 6.2134x over previous
//
#include <hip/hip_runtime.h>
#include <hip/hip_bf16.h>

// CEKT: y_t = sigmoid([h_t|e_t|x] @ Wp + bp)
//   h_t = (1-g)*prev_h + g*tanh(comb @ Wh + bh),  g = sigmoid(comb @ Wq + bq)
//   comb = [e_t | r_t | prev_h];  GAT branch is dead code w.r.t. y_t.
//
// Round-11: revert cooperative (grid.sync costs ~70us on gfx950 - r10 lesson).
// r9 two-kernel structure, plus:
//   - GEMM2 drops the A-side lo term (pure-bf16 A): phase2 MFMA halved,
//     A2l buffer gone, staging work halved.  (GEMM1 keeps 2-term split.)
//   - fast transcendentals (__expf-based sigmoid / NaN-safe tanh) on the
//     serial between-barriers epilogue path.

typedef short s16x8 __attribute__((ext_vector_type(8)));
typedef float f32x4 __attribute__((ext_vector_type(4)));

constexpr int NKQ = 10;  // K1=320 -> 10 ksteps of 32
constexpr int NKP = 12;  // K2=384 -> 12 ksteps of 32
constexpr int CH_Q = 0, CH_H = 80, CH_P = 160, NCHUNK = 256;

__device__ __forceinline__ ushort bf16_rne(float f) {
    union { float f; uint u; } a; a.f = f;
    return (ushort)((a.u + 0x7FFFu + ((a.u >> 16) & 1u)) >> 16);
}
__device__ __forceinline__ float bf16_to_f(ushort h) {
    union { uint u; float f; } b; b.u = ((uint)h) << 16;
    return b.f;
}
__device__ __forceinline__ void split2(float f, ushort& hi, ushort& lo) {
    hi = bf16_rne(f);
    lo = bf16_rne(f - bf16_to_f(hi));
}
__device__ __forceinline__ float fsigmoid(float z) {
    return 1.0f / (1.0f + __expf(-z));
}
__device__ __forceinline__ float ftanh(float z) {
    const float a = fabsf(z);
    const float t = __expf(-2.0f * a);           // (0,1], no overflow
    const float r = (1.0f - t) / (1.0f + t);
    return copysignf(r, z);
}

// ---------------- prep: weights -> B-frag bf16 (hi only) in d_ws ------------
// frag elem (chunk, l, j):  W[s*32 + (l>>4)*8 + j][ct*16 + (l&15)]
__global__ __launch_bounds__(128) void prep_w(
    const float* __restrict__ Wq, const float* __restrict__ Wh,
    const float* __restrict__ Wp, ushort* __restrict__ ws)
{
    const int chunk = blockIdx.x;          // 0..255
    const int t = threadIdx.x;
    const int jp = t >> 6, l = t & 63;
    const float* W;
    int s, ct;
    if (chunk < CH_H)      { W = Wq; ct = chunk / NKQ;          s = chunk % NKQ; }
    else if (chunk < CH_P) { W = Wh; ct = (chunk - CH_H) / NKQ; s = (chunk - CH_H) % NKQ; }
    else                   { W = Wp; ct = (chunk - CH_P) / NKP; s = (chunk - CH_P) % NKP; }
    const int col = ct * 16 + (l & 15);
    const int kbase = s * 32 + (l >> 4) * 8 + jp * 4;
    ushort hi[4];
#pragma unroll
    for (int j2 = 0; j2 < 4; ++j2)
        hi[j2] = bf16_rne(W[(kbase + j2) * 128 + col]);
    const int ub = (chunk * 64 + l) * 8 + jp * 4;   // ushort offset
    *(uint2*)&ws[ub] = *(const uint2*)hi;
}

// ---------------- main ----------------
__global__ __launch_bounds__(1024, 1) void cekt_mfma(
    const float* __restrict__ x,
    const float* __restrict__ e_t,
    const float* __restrict__ r_t,
    const float* __restrict__ prev_h,
    const float* __restrict__ bq,
    const float* __restrict__ bh,
    const float* __restrict__ bp,
    const ushort* __restrict__ ws,
    float* __restrict__ out)
{
    __shared__ alignas(16) ushort A1h[NKQ * 64 * 8], A1l[NKQ * 64 * 8];
    __shared__ alignas(16) ushort A2h[NKP * 64 * 8];
    __shared__ f32x4 p1g[8][64], p1c[8][64], p2y[8][64];

    const int t = threadIdx.x;
    const int row0 = blockIdx.x * 16;
    const int w = t >> 6, lane = t & 63;
    const int ct = w & 7, kh = w >> 3;

    const s16x8* whv = (const s16x8*)ws;

    // ---- stage A1 (comb1) hi+lo, coalesced float4 per row ----
    for (int i = t; i < 1280; i += 1024) {
        const int row = i / 80, kq4 = i - row * 80;
        const int k0 = kq4 * 4;
        float4 v;
        if (k0 < 128)      v = *(const float4*)&e_t[(row0 + row) * 128 + k0];
        else if (k0 < 192) v = *(const float4*)&r_t[(row0 + row) * 64 + (k0 - 128)];
        else               v = *(const float4*)&prev_h[(row0 + row) * 128 + (k0 - 192)];
        const int s = k0 >> 5, q = (k0 >> 3) & 3, j0 = k0 & 7;
        const int base = (s * 64 + q * 16 + row) * 8 + j0;
        ushort hi4[4], lo4[4];
        split2(v.x, hi4[0], lo4[0]); split2(v.y, hi4[1], lo4[1]);
        split2(v.z, hi4[2], lo4[2]); split2(v.w, hi4[3], lo4[3]);
        *(uint2*)&A1h[base] = *(const uint2*)hi4;
        *(uint2*)&A1l[base] = *(const uint2*)lo4;
    }
    // ---- stage A2 static part (s=4..11: e_t | x), hi only ----
    {
        const int row = t >> 6, kr = t & 63;
        const int k0 = 128 + kr * 4;            // 128..380
        const float4 v = (k0 < 256)
            ? *(const float4*)&e_t[(row0 + row) * 128 + (k0 - 128)]
            : *(const float4*)&x[(row0 + row) * 128 + (k0 - 256)];
        const int s = k0 >> 5, q = (k0 >> 3) & 3, j0 = k0 & 7;
        const int base = (s * 64 + q * 16 + row) * 8 + j0;
        ushort hi4[4];
        hi4[0] = bf16_rne(v.x); hi4[1] = bf16_rne(v.y);
        hi4[2] = bf16_rne(v.z); hi4[3] = bf16_rne(v.w);
        *(uint2*)&A2h[base] = *(const uint2*)hi4;
    }

    // ---- hoist: ALL phase1 B frags (hi only, 5 ksteps x {q,c}) ----
    const int sbeg = kh * 5;
    s16x8 hq[5], hc[5];
#pragma unroll
    for (int si = 0; si < 5; ++si) {
        const int cq = (CH_Q + ct * NKQ + sbeg + si) * 64 + lane;
        const int cc = (CH_H + ct * NKQ + sbeg + si) * 64 + lane;
        hq[si] = whv[cq];
        hc[si] = whv[cc];
    }
    __syncthreads();                                        // barrier 1

    // ---- phase 1: g,cand partials (2-term split on A), pure LDS+MFMA ----
    f32x4 gacc = {0, 0, 0, 0}, cacc = {0, 0, 0, 0};
#pragma unroll
    for (int si = 0; si < 5; ++si) {
        const int s = sbeg + si;
        const s16x8 aH = *(const s16x8*)&A1h[(s * 64 + lane) * 8];
        const s16x8 aL = *(const s16x8*)&A1l[(s * 64 + lane) * 8];
        gacc = __builtin_amdgcn_mfma_f32_16x16x32_bf16(aH, hq[si], gacc, 0, 0, 0);
        cacc = __builtin_amdgcn_mfma_f32_16x16x32_bf16(aH, hc[si], cacc, 0, 0, 0);
        gacc = __builtin_amdgcn_mfma_f32_16x16x32_bf16(aL, hq[si], gacc, 0, 0, 0);
        cacc = __builtin_amdgcn_mfma_f32_16x16x32_bf16(aL, hc[si], cacc, 0, 0, 0);
    }

    // kh1: store partials, then prefetch phase2-static B across barrier2
    s16x8 pH[6];
    if (kh) {
        p1g[ct][lane] = gacc;
        p1c[ct][lane] = cacc;
#pragma unroll
        for (int si = 0; si < 6; ++si)
            pH[si] = whv[(CH_P + ct * NKP + 6 + si) * 64 + lane];
    }
    __syncthreads();                                        // barrier 2

    f32x4 yacc = {0, 0, 0, 0};
    s16x8 rH[6];
    if (!kh) {
        // issue phase2-remainder B loads first; epilogue VALU covers latency
#pragma unroll
        for (int si = 0; si < 6; ++si)
            rH[si] = whv[(CH_P + ct * NKP + si) * 64 + lane];
        // ---- reduce + gate epilogue; h_t written directly in A2-frag layout
        gacc += p1g[ct][lane];
        cacc += p1c[ct][lane];
        const int colL = lane & 15, rg = lane >> 4;
        const int col = ct * 16 + colL;
        const float bqv = bq[col], bhv = bh[col];
        const int s_h = col >> 5, q_h = (col >> 3) & 3, j_h = col & 7;
#pragma unroll
        for (int i2 = 0; i2 < 4; ++i2) {
            const int row = rg * 4 + i2;
            const float ph = prev_h[(row0 + row) * 128 + col];
            const float g = fsigmoid(gacc[i2] + bqv);
            const float cd = ftanh(cacc[i2] + bhv);
            const float h = (1.0f - g) * ph + g * cd;
            const int idx = (s_h * 64 + q_h * 16 + row) * 8 + j_h;
            A2h[idx] = bf16_rne(h);
        }
    } else {
        // ---- phase 2 partials over static ksteps s=6..11 (preloaded B) ----
#pragma unroll
        for (int si = 0; si < 6; ++si) {
            const int s = 6 + si;
            const s16x8 aH = *(const s16x8*)&A2h[(s * 64 + lane) * 8];
            yacc = __builtin_amdgcn_mfma_f32_16x16x32_bf16(aH, pH[si], yacc, 0, 0, 0);
        }
        p2y[ct][lane] = yacc;
    }
    __syncthreads();                                        // barrier 3

    // ---- phase 2 remainder (s=0..5, contains h_t) + output, kh0 waves ----
    if (!kh) {
        yacc = p2y[ct][lane];
#pragma unroll
        for (int si = 0; si < 6; ++si) {
            const s16x8 aH = *(const s16x8*)&A2h[(si * 64 + lane) * 8];
            yacc = __builtin_amdgcn_mfma_f32_16x16x32_bf16(aH, rH[si], yacc, 0, 0, 0);
        }
        const int colL = lane & 15, rg = lane >> 4;
        const int col = ct * 16 + colL;
        const float bpv = bp[col];
#pragma unroll
        for (int i2 = 0; i2 < 4; ++i2) {
            const int row = rg * 4 + i2;
            out[(row0 + row) * 128 + col] = fsigmoid(yacc[i2] + bpv);
        }
    }
}

extern "C" void kernel_launch(void* const* d_in, const int* in_sizes, int n_in,
                              void* d_out, int out_size, void* d_ws, size_t ws_size,
                              hipStream_t stream) {
    // setup_inputs order:
    // 0:x 1:adj 2:e_t 3:r_t 4:prev_h 5:W_heads 6:a_heads 7:W_out 8:a_out
    // 9:Wq_w 10:Wq_b 11:Wh_w 12:Wh_b 13:Wp_w 14:Wp_b
    const float* x      = (const float*)d_in[0];
    const float* e_t    = (const float*)d_in[2];
    const float* r_t    = (const float*)d_in[3];
    const float* prev_h = (const float*)d_in[4];
    const float* Wq_w   = (const float*)d_in[9];
    const float* Wq_b   = (const float*)d_in[10];
    const float* Wh_w   = (const float*)d_in[11];
    const float* Wh_b   = (const float*)d_in[12];
    const float* Wp_w   = (const float*)d_in[13];
    const float* Wp_b   = (const float*)d_in[14];
    float* out  = (float*)d_out;
    ushort* ws  = (ushort*)d_ws;   // 256 KB used

    hipLaunchKernelGGL(prep_w, dim3(NCHUNK), dim3(128), 0, stream,
                       Wq_w, Wh_w, Wp_w, ws);
    hipLaunchKernelGGL(cekt_mfma, dim3(256), dim3(1024), 0, stream,
                       x, e_t, r_t, prev_h, Wq_b, Wh_b, Wp_b, ws, out);
}